// Round 16
// baseline (40.243 us; speedup 1.0000x reference)
//
#include <hip/hip_runtime.h>
#include <hip/hip_bf16.h>

typedef _Float16 half8 __attribute__((ext_vector_type(8)));
typedef float f32x4 __attribute__((ext_vector_type(4)));
typedef unsigned int u32x4 __attribute__((ext_vector_type(4)));

#define N_U      4096
#define N_L      65536
#define NZ       32
#define NSPLIT   256                  // L splits (grid.x of kA)
#define LSLICE   (N_L / NSPLIT)       // 256 L rows per block -> 16 tiles
#define NT       (LSLICE / 16)        // 16 L-tiles per block
#define UT       16                   // u-tiles per wave (16 MFMA per A-load)
#define BM       1024                 // U rows per kA block (4 waves x 16 x 16)
#define GY       (N_U / BM)           // 4

// workspace layout
#define OFF_P1   0                            // u32 P1key[N_U] (16 KB)
#define OFF_USQ  (16 * 1024)                  // float usq[N_U]  (16 KB)
#define OFF_LF   (32 * 1024)                  // _Float16 Lf16[N_L][32] (4 MB)
#define OFF_LSQ  (OFF_LF + N_L * NZ * 2)      // float lsqh[N_L] = -0.5*||l||^2
#define OFF_UF   (OFF_LSQ + N_L * 4)          // _Float16 Uf16[N_U][32]

// Order-preserving float <-> uint key (monotone for all finite floats)
__device__ __forceinline__ unsigned int f2key(float f) {
    unsigned int u = __float_as_uint(f);
    return (u & 0x80000000u) ? ~u : (u | 0x80000000u);
}
__device__ __forceinline__ float key2f(unsigned int k) {
    unsigned int u = (k & 0x80000000u) ? (k & 0x7FFFFFFFu) : ~k;
    return __uint_as_float(u);
}

// ---------------------------------------------------------------------------
// Precompute: L -> f16 + (-0.5*||l||^2); U -> f16 + ||u||^2; init P1key.
__global__ __launch_bounds__(256) void kPre(const float* __restrict__ Uz,
                                            const float* __restrict__ Lz,
                                            _Float16* __restrict__ Lf16,
                                            float* __restrict__ lsqh,
                                            _Float16* __restrict__ Uf16,
                                            float* __restrict__ usq,
                                            unsigned int* __restrict__ P1key) {
    int r = blockIdx.x * 256 + threadIdx.x;
    if (r < N_L) {
        const f32x4* src = (const f32x4*)(Lz + (size_t)r * NZ);
        _Float16* dst = Lf16 + (size_t)r * NZ;
        float s = 0.f;
#pragma unroll
        for (int j = 0; j < 4; ++j) {
            f32x4 a = src[2 * j], b = src[2 * j + 1];
            s = fmaf(a[0], a[0], s); s = fmaf(a[1], a[1], s);
            s = fmaf(a[2], a[2], s); s = fmaf(a[3], a[3], s);
            s = fmaf(b[0], b[0], s); s = fmaf(b[1], b[1], s);
            s = fmaf(b[2], b[2], s); s = fmaf(b[3], b[3], s);
            *(half8*)(dst + j * 8) =
                (half8){(_Float16)a[0], (_Float16)a[1], (_Float16)a[2], (_Float16)a[3],
                        (_Float16)b[0], (_Float16)b[1], (_Float16)b[2], (_Float16)b[3]};
        }
        lsqh[r] = -0.5f * s;
    } else if (r < N_L + N_U) {
        int u = r - N_L;
        const f32x4* src = (const f32x4*)(Uz + (size_t)u * NZ);
        _Float16* dst = Uf16 + (size_t)u * NZ;
        float s = 0.f;
#pragma unroll
        for (int j = 0; j < 4; ++j) {
            f32x4 a = src[2 * j], b = src[2 * j + 1];
            s = fmaf(a[0], a[0], s); s = fmaf(a[1], a[1], s);
            s = fmaf(a[2], a[2], s); s = fmaf(a[3], a[3], s);
            s = fmaf(b[0], b[0], s); s = fmaf(b[1], b[1], s);
            s = fmaf(b[2], b[2], s); s = fmaf(b[3], b[3], s);
            *(half8*)(dst + j * 8) =
                (half8){(_Float16)a[0], (_Float16)a[1], (_Float16)a[2], (_Float16)a[3],
                        (_Float16)b[0], (_Float16)b[1], (_Float16)b[2], (_Float16)b[3]};
        }
        usq[u] = s;
        P1key[u] = 0u;   // key-space -inf
    }
}

// ---------------------------------------------------------------------------
// Heavy kernel: atomicMax over L-slices of key(u.l - 0.5*||l||^2).
// R15 structure (UT=16 + pinned bfrag + wave stagger, 1024 blocks = 4/CU).
// NEW: amdgpu_waves_per_eu(4,4) — the MAX bound stops the allocator from
// chasing >4 waves/EU occupancy by minimizing arch VGPRs. R6-R15 showed
// VGPR_Count 36-60 with accumulators in AGPRs: every MFMA paid ~8 accvgpr
// moves (C-in write + D-out read), ~4x the intended VALU (R13: 19.7k
// measured vs 5k source-level SIMD-cyc). With a 128-reg/wave budget the
// ~110-reg live set fits as pure VGPRs -> VGPR-form MFMA, zero accvgpr churn.
__global__ __launch_bounds__(256)
__attribute__((amdgpu_waves_per_eu(4, 4)))
void kA(const _Float16* __restrict__ Lf16,
        const float* __restrict__ lsqh,
        const _Float16* __restrict__ Uf16,
        unsigned int* __restrict__ P1key) {
    const int tid  = threadIdx.x;
    const int lane = tid & 63;
    const int wave = tid >> 6;
    const int g    = lane >> 4;    // k-chunk 0..3 (k = g*8+e, same perm A and B)
    const int lc   = lane & 15;

    const int ubase = blockIdx.y * BM + wave * (UT * 16);
    const int lbase = blockIdx.x * LSLICE;

    half8 bfrag[UT];
#pragma unroll
    for (int t = 0; t < UT; ++t)
        bfrag[t] = *(const half8*)(Uf16 + (size_t)(ubase + t * 16 + lc) * NZ + g * 8);
    // Pin B-fragments: opaque non-rematerializable defs (R13: kept resident).
#pragma unroll
    for (int t = 0; t < UT; ++t)
        asm volatile("" : "+v"(bfrag[t]));

    float m[UT];
#pragma unroll
    for (int t = 0; t < UT; ++t) m[t] = -INFINITY;

    // tile i: A at ap[i*64] (16 rows x 32 f16 / 8 elems), C at cp[i*4]
    const half8* ap = (const half8*)(Lf16 + (size_t)(lbase + lc) * NZ + g * 8);
    const f32x4* cp = (const f32x4*)(lsqh + lbase + g * 4);

#pragma unroll 2
    for (int lt = 0; lt < NT; ++lt) {
        const int pt = (lt + wave * 4) & (NT - 1);   // per-wave phase stagger
        half8 a = ap[(size_t)pt * 64];
        f32x4 c = cp[pt * 4];
#pragma unroll
        for (int t = 0; t < UT; ++t) {
            f32x4 x = __builtin_amdgcn_mfma_f32_16x16x32_f16(a, bfrag[t], c, 0, 0, 0);
            float y = fmaxf(fmaxf(x[0], x[1]), x[2]);        // v_max3
            m[t] = fmaxf(fmaxf(y, x[3]), m[t]);              // v_max3
        }
    }

#pragma unroll
    for (int t = 0; t < UT; ++t) {
        float v = m[t];
        v = fmaxf(v, __shfl_xor(v, 16));
        v = fmaxf(v, __shfl_xor(v, 32));
        if (g == 0)
            atomicMax(&P1key[ubase + t * 16 + lc], f2key(v));
    }
}

// ---------------------------------------------------------------------------
// Single-block finisher: dd, global min/max, normalize. Reads 32 KB only.
__global__ __launch_bounds__(1024) void kB(const unsigned int* __restrict__ P1key,
                                           const float* __restrict__ usq,
                                           float* __restrict__ out) {
    const int t    = threadIdx.x;       // 0..1023, each handles 4 u's
    const int lane = t & 63;
    const int wid  = t >> 6;

    u32x4 kv = ((const u32x4*)P1key)[t];
    f32x4 uq = ((const f32x4*)usq)[t];

    float dd[4], lmin = INFINITY, lmax = -INFINITY;
#pragma unroll
    for (int j = 0; j < 4; ++j) {
        float M   = key2f(kv[j]);                       // max(u.l - 0.5||l||^2)
        float sq  = fmaxf(fmaf(-2.f, M, uq[j]), 0.f);   // min squared distance
        float dens = -0.5f * uq[j] - 29.406033062549525f;
        dd[j] = expf(dens) * (sqrtf(sq) + 1e-18f);
        lmin = fminf(lmin, dd[j]);
        lmax = fmaxf(lmax, dd[j]);
    }

    __shared__ float smn[16], smx[16];
#pragma unroll
    for (int o = 1; o < 64; o <<= 1) {
        lmin = fminf(lmin, __shfl_xor(lmin, o));
        lmax = fmaxf(lmax, __shfl_xor(lmax, o));
    }
    if (lane == 0) { smn[wid] = lmin; smx[wid] = lmax; }
    __syncthreads();
    if (wid == 0) {
        float a = (lane < 16) ? smn[lane] : INFINITY;
        float b = (lane < 16) ? smx[lane] : -INFINITY;
#pragma unroll
        for (int o = 1; o < 16; o <<= 1) {
            a = fminf(a, __shfl_xor(a, o));
            b = fmaxf(b, __shfl_xor(b, o));
        }
        if (lane == 0) { smn[0] = a; smx[0] = b; }
    }
    __syncthreads();
    float mn = smn[0], mx = smx[0];
    float inv = 1.f / ((mx - mn) + 1e-18f);

    f32x4 o4 = (f32x4){(dd[0] - mn) * inv, (dd[1] - mn) * inv,
                       (dd[2] - mn) * inv, (dd[3] - mn) * inv};
    ((f32x4*)out)[t] = o4;
}

// ---------------------------------------------------------------------------
extern "C" void kernel_launch(void* const* d_in, const int* in_sizes, int n_in,
                              void* d_out, int out_size, void* d_ws, size_t ws_size,
                              hipStream_t stream) {
    const float* Uz = (const float*)d_in[1];
    const float* Lz = (const float*)d_in[2];
    float* out = (float*)d_out;
    unsigned char* ws = (unsigned char*)d_ws;

    unsigned int* P1key = (unsigned int*)(ws + OFF_P1);
    float*        usq   = (float*)(ws + OFF_USQ);
    _Float16*     Lf16  = (_Float16*)(ws + OFF_LF);
    float*        lsqh  = (float*)(ws + OFF_LSQ);
    _Float16*     Uf16  = (_Float16*)(ws + OFF_UF);

    kPre<<<(N_L + N_U + 255) / 256, 256, 0, stream>>>(Uz, Lz, Lf16, lsqh, Uf16, usq, P1key);
    dim3 grid(NSPLIT, GY);   // 256 x 4 = 1024 blocks = 4/CU, one full round
    kA<<<grid, 256, 0, stream>>>(Lf16, lsqh, Uf16, P1key);
    kB<<<1, 1024, 0, stream>>>(P1key, usq, out);
}

// Round 17
// 34.736 us; speedup vs baseline: 1.1585x; 1.1585x over previous
//
#include <hip/hip_runtime.h>
#include <hip/hip_bf16.h>

typedef _Float16 half8 __attribute__((ext_vector_type(8)));
typedef float f32x4 __attribute__((ext_vector_type(4)));
typedef unsigned int u32x4 __attribute__((ext_vector_type(4)));

#define N_U      4096
#define N_L      65536
#define NZ       32
#define NSPLIT   256                  // L splits (grid.x of kA)
#define LSLICE   (N_L / NSPLIT)       // 256 L rows per block -> 16 tiles
#define NT       (LSLICE / 16)        // 16 L-tiles per block
#define UT       16                   // u-tiles per wave (16 MFMA per A-load)
#define BM       1024                 // U rows per kA block (4 waves x 16 x 16)
#define GY       (N_U / BM)           // 4
#define LDS_STRIDE 80                 // bytes/row: 64B f16 + 16B pad ->
                                      // bank base = lc*20+g*4, 5 coprime 32
                                      // -> 2 lanes/bank on ds_read_b128 (free)

// workspace layout
#define OFF_P1   0                            // u32 P1key[N_U] (16 KB)
#define OFF_USQ  (16 * 1024)                  // float usq[N_U]  (16 KB)
#define OFF_LF   (32 * 1024)                  // _Float16 Lf16[N_L][32] (4 MB)
#define OFF_LSQ  (OFF_LF + N_L * NZ * 2)      // float lsqh[N_L] = -0.5*||l||^2
#define OFF_UF   (OFF_LSQ + N_L * 4)          // _Float16 Uf16[N_U][32]

// Order-preserving float <-> uint key (monotone for all finite floats)
__device__ __forceinline__ unsigned int f2key(float f) {
    unsigned int u = __float_as_uint(f);
    return (u & 0x80000000u) ? ~u : (u | 0x80000000u);
}
__device__ __forceinline__ float key2f(unsigned int k) {
    unsigned int u = (k & 0x80000000u) ? (k & 0x7FFFFFFFu) : ~k;
    return __uint_as_float(u);
}

// ---------------------------------------------------------------------------
// Precompute: L -> f16 + (-0.5*||l||^2); U -> f16 + ||u||^2; init P1key.
__global__ __launch_bounds__(256) void kPre(const float* __restrict__ Uz,
                                            const float* __restrict__ Lz,
                                            _Float16* __restrict__ Lf16,
                                            float* __restrict__ lsqh,
                                            _Float16* __restrict__ Uf16,
                                            float* __restrict__ usq,
                                            unsigned int* __restrict__ P1key) {
    int r = blockIdx.x * 256 + threadIdx.x;
    if (r < N_L) {
        const f32x4* src = (const f32x4*)(Lz + (size_t)r * NZ);
        _Float16* dst = Lf16 + (size_t)r * NZ;
        float s = 0.f;
#pragma unroll
        for (int j = 0; j < 4; ++j) {
            f32x4 a = src[2 * j], b = src[2 * j + 1];
            s = fmaf(a[0], a[0], s); s = fmaf(a[1], a[1], s);
            s = fmaf(a[2], a[2], s); s = fmaf(a[3], a[3], s);
            s = fmaf(b[0], b[0], s); s = fmaf(b[1], b[1], s);
            s = fmaf(b[2], b[2], s); s = fmaf(b[3], b[3], s);
            *(half8*)(dst + j * 8) =
                (half8){(_Float16)a[0], (_Float16)a[1], (_Float16)a[2], (_Float16)a[3],
                        (_Float16)b[0], (_Float16)b[1], (_Float16)b[2], (_Float16)b[3]};
        }
        lsqh[r] = -0.5f * s;
    } else if (r < N_L + N_U) {
        int u = r - N_L;
        const f32x4* src = (const f32x4*)(Uz + (size_t)u * NZ);
        _Float16* dst = Uf16 + (size_t)u * NZ;
        float s = 0.f;
#pragma unroll
        for (int j = 0; j < 4; ++j) {
            f32x4 a = src[2 * j], b = src[2 * j + 1];
            s = fmaf(a[0], a[0], s); s = fmaf(a[1], a[1], s);
            s = fmaf(a[2], a[2], s); s = fmaf(a[3], a[3], s);
            s = fmaf(b[0], b[0], s); s = fmaf(b[1], b[1], s);
            s = fmaf(b[2], b[2], s); s = fmaf(b[3], b[3], s);
            *(half8*)(dst + j * 8) =
                (half8){(_Float16)a[0], (_Float16)a[1], (_Float16)a[2], (_Float16)a[3],
                        (_Float16)b[0], (_Float16)b[1], (_Float16)b[2], (_Float16)b[3]};
        }
        usq[u] = s;
        P1key[u] = 0u;   // key-space -inf
    }
}

// ---------------------------------------------------------------------------
// Heavy kernel: atomicMax over L-slices of key(u.l - 0.5*||l||^2).
// R11 retried with correct register budget: L-slice staged ONCE per block in
// LDS (stride-80 rows -> 2-way banks, free), one barrier, then 16 iters of
// {ds_read_b128 A (~120 cyc, hidden) + 16 MFMA}. Kills the per-iteration
// ~600-cyc L3-latency exposure that capped warm MfmaUtil at 34.7% (R13:
// 310-cyc burst / (310+600) = 34% duty = measured). waves_per_eu(4,4)
// (R16-proven safe) gives the 128-reg budget the ~110-reg live set needs.
__global__ __launch_bounds__(256)
__attribute__((amdgpu_waves_per_eu(4, 4)))
void kA(const _Float16* __restrict__ Lf16,
        const float* __restrict__ lsqh,
        const _Float16* __restrict__ Uf16,
        unsigned int* __restrict__ P1key) {
    __shared__ __align__(16) unsigned char sm[LSLICE * LDS_STRIDE + LSLICE * 4];
    float* slsq = (float*)(sm + LSLICE * LDS_STRIDE);

    const int tid  = threadIdx.x;
    const int lane = tid & 63;
    const int wave = tid >> 6;
    const int g    = lane >> 4;    // k-chunk 0..3 (k = g*8+e, same perm A and B)
    const int lc   = lane & 15;

    const int ubase = blockIdx.y * BM + wave * (UT * 16);
    const int lbase = blockIdx.x * LSLICE;

    // ---- stage: thread t -> L row t (4 x 16B, coalesced global, 2-way LDS)
    {
        const half8* src = (const half8*)(Lf16 + (size_t)(lbase + tid) * NZ);
        unsigned char* dst = sm + tid * LDS_STRIDE;
#pragma unroll
        for (int j = 0; j < 4; ++j)
            *(half8*)(dst + j * 16) = src[j];
        slsq[tid] = lsqh[lbase + tid];
    }

    half8 bfrag[UT];
#pragma unroll
    for (int t = 0; t < UT; ++t)
        bfrag[t] = *(const half8*)(Uf16 + (size_t)(ubase + t * 16 + lc) * NZ + g * 8);
    // Pin B-fragments: opaque non-rematerializable defs (R13: kept resident).
#pragma unroll
    for (int t = 0; t < UT; ++t)
        asm volatile("" : "+v"(bfrag[t]));

    float m[UT];
#pragma unroll
    for (int t = 0; t < UT; ++t) m[t] = -INFINITY;

    __syncthreads();

    const unsigned char* abase = sm + lc * LDS_STRIDE + g * 16;

#pragma unroll 2
    for (int lt = 0; lt < NT; ++lt) {
        const int pt = (lt + wave * 4) & (NT - 1);   // per-wave phase stagger
        half8 a = *(const half8*)(abase + pt * (16 * LDS_STRIDE));
        f32x4 c = *(const f32x4*)(slsq + pt * 16 + g * 4);   // 16-lane broadcast
#pragma unroll
        for (int t = 0; t < UT; ++t) {
            f32x4 x = __builtin_amdgcn_mfma_f32_16x16x32_f16(a, bfrag[t], c, 0, 0, 0);
            float y = fmaxf(fmaxf(x[0], x[1]), x[2]);        // v_max3
            m[t] = fmaxf(fmaxf(y, x[3]), m[t]);              // v_max3
        }
    }

#pragma unroll
    for (int t = 0; t < UT; ++t) {
        float v = m[t];
        v = fmaxf(v, __shfl_xor(v, 16));
        v = fmaxf(v, __shfl_xor(v, 32));
        if (g == 0)
            atomicMax(&P1key[ubase + t * 16 + lc], f2key(v));
    }
}

// ---------------------------------------------------------------------------
// Single-block finisher: dd, global min/max, normalize. Reads 32 KB only.
__global__ __launch_bounds__(1024) void kB(const unsigned int* __restrict__ P1key,
                                           const float* __restrict__ usq,
                                           float* __restrict__ out) {
    const int t    = threadIdx.x;       // 0..1023, each handles 4 u's
    const int lane = t & 63;
    const int wid  = t >> 6;

    u32x4 kv = ((const u32x4*)P1key)[t];
    f32x4 uq = ((const f32x4*)usq)[t];

    float dd[4], lmin = INFINITY, lmax = -INFINITY;
#pragma unroll
    for (int j = 0; j < 4; ++j) {
        float M   = key2f(kv[j]);                       // max(u.l - 0.5||l||^2)
        float sq  = fmaxf(fmaf(-2.f, M, uq[j]), 0.f);   // min squared distance
        float dens = -0.5f * uq[j] - 29.406033062549525f;
        dd[j] = expf(dens) * (sqrtf(sq) + 1e-18f);
        lmin = fminf(lmin, dd[j]);
        lmax = fmaxf(lmax, dd[j]);
    }

    __shared__ float smn[16], smx[16];
#pragma unroll
    for (int o = 1; o < 64; o <<= 1) {
        lmin = fminf(lmin, __shfl_xor(lmin, o));
        lmax = fmaxf(lmax, __shfl_xor(lmax, o));
    }
    if (lane == 0) { smn[wid] = lmin; smx[wid] = lmax; }
    __syncthreads();
    if (wid == 0) {
        float a = (lane < 16) ? smn[lane] : INFINITY;
        float b = (lane < 16) ? smx[lane] : -INFINITY;
#pragma unroll
        for (int o = 1; o < 16; o <<= 1) {
            a = fminf(a, __shfl_xor(a, o));
            b = fmaxf(b, __shfl_xor(b, o));
        }
        if (lane == 0) { smn[0] = a; smx[0] = b; }
    }
    __syncthreads();
    float mn = smn[0], mx = smx[0];
    float inv = 1.f / ((mx - mn) + 1e-18f);

    f32x4 o4 = (f32x4){(dd[0] - mn) * inv, (dd[1] - mn) * inv,
                       (dd[2] - mn) * inv, (dd[3] - mn) * inv};
    ((f32x4*)out)[t] = o4;
}

// ---------------------------------------------------------------------------
extern "C" void kernel_launch(void* const* d_in, const int* in_sizes, int n_in,
                              void* d_out, int out_size, void* d_ws, size_t ws_size,
                              hipStream_t stream) {
    const float* Uz = (const float*)d_in[1];
    const float* Lz = (const float*)d_in[2];
    float* out = (float*)d_out;
    unsigned char* ws = (unsigned char*)d_ws;

    unsigned int* P1key = (unsigned int*)(ws + OFF_P1);
    float*        usq   = (float*)(ws + OFF_USQ);
    _Float16*     Lf16  = (_Float16*)(ws + OFF_LF);
    float*        lsqh  = (float*)(ws + OFF_LSQ);
    _Float16*     Uf16  = (_Float16*)(ws + OFF_UF);

    kPre<<<(N_L + N_U + 255) / 256, 256, 0, stream>>>(Uz, Lz, Lf16, lsqh, Uf16, usq, P1key);
    dim3 grid(NSPLIT, GY);   // 256 x 4 = 1024 blocks = 4/CU, one full round
    kA<<<grid, 256, 0, stream>>>(Lf16, lsqh, Uf16, P1key);
    kB<<<1, 1024, 0, stream>>>(P1key, usq, out);
}